// Round 1
// baseline (19579.530 us; speedup 1.0000x reference)
//
#include <hip/hip_runtime.h>
#include <math.h>

#define BATCH 8192
#define FEAT  64
#define HID   512
#define NS    16   // RK4 steps

// ---------------------------------------------------------------------------
// Tiled GEMM: out[i][j] = epilogue( bias[j] + t*trow[j] + sum_k A[i][k]*W[k][j] )
// M=8192 rows, N=512 cols fixed. lda == K. 16 rows per block, 256 cols handled
// per block (2 col-blocks per row group). emode: 0=linear, 1=tanh (+optional
// out2 = aux*(1-v^2), aux=g3), 2 = v*(1-aux^2) (aux=h1, for backward).
// ---------------------------------------------------------------------------
__global__ __launch_bounds__(256) void mlp_gemm(
    const float* __restrict__ A, const float* __restrict__ W,
    const float* __restrict__ bias, const float* __restrict__ trow, float tval,
    float* __restrict__ out, const float* __restrict__ aux, float* __restrict__ out2,
    int K, int emode)
{
    const int bid  = blockIdx.x;
    const int row0 = (bid >> 1) << 4;                 // 16 rows / block
    const int j    = ((bid & 1) << 8) + threadIdx.x;  // output column

    __shared__ float As[16 * 64];
    float acc[16];
#pragma unroll
    for (int r = 0; r < 16; ++r) acc[r] = 0.f;

    for (int k0 = 0; k0 < K; k0 += 64) {
        __syncthreads();
        for (int tt = threadIdx.x; tt < 16 * 64; tt += 256) {
            int r = tt >> 6, k = tt & 63;
            As[tt] = A[(size_t)(row0 + r) * K + (k0 + k)];
        }
        __syncthreads();
        for (int k = 0; k < 64; k += 4) {
            float w0 = W[(size_t)(k0 + k + 0) * HID + j];
            float w1 = W[(size_t)(k0 + k + 1) * HID + j];
            float w2 = W[(size_t)(k0 + k + 2) * HID + j];
            float w3 = W[(size_t)(k0 + k + 3) * HID + j];
#pragma unroll
            for (int r = 0; r < 16; ++r) {
                float4 a = *(const float4*)&As[r * 64 + k];
                acc[r] += a.x * w0 + a.y * w1 + a.z * w2 + a.w * w3;
            }
        }
    }

    float b = bias ? bias[j] : 0.f;
    if (trow) b += tval * trow[j];
#pragma unroll
    for (int r = 0; r < 16; ++r) {
        size_t o = (size_t)(row0 + r) * HID + j;
        float v = acc[r] + b;
        if (emode == 1) {
            v = tanhf(v);
            out[o] = v;
            if (out2) out2[o] = aux[o] * (1.f - v * v);
        } else if (emode == 2) {
            float hv = aux[o];
            out[o] = v * (1.f - hv * hv);
        } else {
            out[o] = v;
        }
    }
}

// dx[i][f] = b3[f] + sum_h h2[i][h] * W3[h][f]    (N=64, K=512)
__global__ __launch_bounds__(256) void dx_kernel(
    const float* __restrict__ h2, const float* __restrict__ W3,
    const float* __restrict__ b3, float* __restrict__ dx)
{
    int i = (blockIdx.x << 2) + (threadIdx.x >> 6);
    int f = threadIdx.x & 63;
    const float* hrow = h2 + (size_t)i * HID;
    float acc = 0.f;
    for (int h = 0; h < HID; ++h) acc += hrow[h] * W3[h * 64 + f];
    dx[(size_t)i * 64 + f] = acc + b3[f];
}

// tr[i] = sum_h g1[i][h] * E1[i][h]   (one wave per row, 4 rows per block)
__global__ __launch_bounds__(256) void tr_kernel(
    const float* __restrict__ g1, const float* __restrict__ E1,
    float* __restrict__ tr)
{
    int i = (blockIdx.x << 2) + (threadIdx.x >> 6);
    int lane = threadIdx.x & 63;
    size_t base = (size_t)i * HID;
    float s = 0.f;
    for (int h = lane; h < HID; h += 64) s += g1[base + h] * E1[base + h];
#pragma unroll
    for (int off = 32; off; off >>= 1) s += __shfl_down(s, off);
    if (lane == 0) tr[i] = s;
}

__global__ void transpose_kernel(const float* __restrict__ in, float* __restrict__ out,
                                 int R, int C)
{
    int idx = blockIdx.x * 256 + threadIdx.x;
    if (idx < R * C) { int r = idx / C, c = idx % C; out[c * R + r] = in[idx]; }
}

__global__ __launch_bounds__(256) void axpy_kernel(
    const float* __restrict__ X, const float* __restrict__ kk, float c,
    float* __restrict__ Xe)
{
    int n = blockIdx.x * 256 + threadIdx.x;
    Xe[n] = X[n] + c * kk[n];
}

__global__ __launch_bounds__(256) void combine_kernel(
    float* __restrict__ X, const float* __restrict__ k1, const float* __restrict__ k2,
    const float* __restrict__ k3, const float* __restrict__ k4, float h6)
{
    int n = blockIdx.x * 256 + threadIdx.x;
    X[n] += h6 * (k1[n] + 2.f * k2[n] + 2.f * k3[n] + k4[n]);
}

__global__ __launch_bounds__(256) void ldcombine_kernel(
    float* __restrict__ ld, const float* __restrict__ t1, const float* __restrict__ t2,
    const float* __restrict__ t3, const float* __restrict__ t4, float h6)
{
    int n = blockIdx.x * 256 + threadIdx.x;
    ld[n] -= h6 * (t1[n] + 2.f * t2[n] + 2.f * t3[n] + t4[n]);
}

__global__ __launch_bounds__(256) void copy_kernel(const float* __restrict__ in,
                                                   float* __restrict__ out, int n)
{
    int i = blockIdx.x * 256 + threadIdx.x;
    if (i < n) out[i] = in[i];
}

__global__ __launch_bounds__(256) void zero_kernel(float* __restrict__ p, int n)
{
    int i = blockIdx.x * 256 + threadIdx.x;
    if (i < n) p[i] = 0.f;
}

__global__ __launch_bounds__(256) void final_kernel(
    const float* __restrict__ X, const float* __restrict__ ld, float* __restrict__ out)
{
    int n = blockIdx.x * 256 + threadIdx.x;
    const int NZ = BATCH * FEAT;
    if (n < NZ) out[n] = X[n];
    else if (n < NZ + BATCH) out[n] = ld[n - NZ];
}

extern "C" void kernel_launch(void* const* d_in, const int* in_sizes, int n_in,
                              void* d_out, int out_size, void* d_ws, size_t ws_size,
                              hipStream_t stream)
{
    const float* x   = (const float*)d_in[0];
    const float* eps = (const float*)d_in[1];
    const float* W1  = (const float*)d_in[2];
    const float* b1  = (const float*)d_in[3];
    const float* W2  = (const float*)d_in[4];
    const float* b2  = (const float*)d_in[5];
    const float* W3  = (const float*)d_in[6];
    const float* b3  = (const float*)d_in[7];

    float* ws = (float*)d_ws;
    size_t off = 0;
    auto alloc = [&](size_t n) { float* p = ws + off; off += n; return p; };

    float* g3  = alloc((size_t)BATCH * HID);
    float* E1  = alloc((size_t)BATCH * HID);
    float* h1  = alloc((size_t)BATCH * HID);
    float* h2  = alloc((size_t)BATCH * HID);
    float* g2  = alloc((size_t)BATCH * HID);
    float* g1  = alloc((size_t)BATCH * HID);
    float* W2T = alloc((size_t)HID * HID);
    float* W3T = alloc((size_t)HID * FEAT);
    float* X   = alloc((size_t)BATCH * FEAT);
    float* Xe  = alloc((size_t)BATCH * FEAT);
    float* k1  = alloc((size_t)BATCH * FEAT);
    float* k2  = alloc((size_t)BATCH * FEAT);
    float* k3  = alloc((size_t)BATCH * FEAT);
    float* k4  = alloc((size_t)BATCH * FEAT);
    float* tr1 = alloc(BATCH);
    float* tr2 = alloc(BATCH);
    float* tr3 = alloc(BATCH);
    float* tr4 = alloc(BATCH);
    float* ld  = alloc(BATCH);
    (void)ws_size; (void)in_sizes; (void)n_in; (void)out_size;

    // One-time (per call) precompute: transposes + constant backward terms.
    transpose_kernel<<<(HID * HID + 255) / 256, 256, 0, stream>>>(W2, W2T, HID, HID);
    transpose_kernel<<<(HID * FEAT + 255) / 256, 256, 0, stream>>>(W3, W3T, HID, FEAT);
    // g3 = eps @ W3^T   (constant over t);  E1 = eps @ W1[:64]
    mlp_gemm<<<1024, 256, 0, stream>>>(eps, W3T, nullptr, nullptr, 0.f,
                                       g3, nullptr, nullptr, 64, 0);
    mlp_gemm<<<1024, 256, 0, stream>>>(eps, W1, nullptr, nullptr, 0.f,
                                       E1, nullptr, nullptr, 64, 0);

    copy_kernel<<<2048, 256, 0, stream>>>(x, X, BATCH * FEAT);
    zero_kernel<<<32, 256, 0, stream>>>(ld, BATCH);

    const float hstep = 1.f / NS;
    float* kbuf[4]  = {k1, k2, k3, k4};
    float* trbuf[4] = {tr1, tr2, tr3, tr4};

    for (int s = 0; s < NS; ++s) {
        float t0 = s * hstep;
        const float cs[4] = {0.f, 0.5f * hstep, 0.5f * hstep, hstep};
        const float tsv[4] = {t0, t0 + 0.5f * hstep, t0 + 0.5f * hstep, t0 + hstep};
        for (int st = 0; st < 4; ++st) {
            const float* Xin;
            if (st == 0) Xin = X;
            else {
                axpy_kernel<<<2048, 256, 0, stream>>>(X, kbuf[st - 1], cs[st], Xe);
                Xin = Xe;
            }
            // h1 = tanh([Xin, t] @ W1 + b1)
            mlp_gemm<<<1024, 256, 0, stream>>>(Xin, W1, b1, W1 + (size_t)64 * HID,
                                               tsv[st], h1, nullptr, nullptr, 64, 1);
            // h2 = tanh(h1 @ W2 + b2); g2 = g3 * (1 - h2^2)
            mlp_gemm<<<1024, 256, 0, stream>>>(h1, W2, b2, nullptr, 0.f,
                                               h2, g3, g2, 512, 1);
            // dx = h2 @ W3 + b3
            dx_kernel<<<2048, 256, 0, stream>>>(h2, W3, b3, kbuf[st]);
            // g1 = (g2 @ W2^T) * (1 - h1^2)
            mlp_gemm<<<1024, 256, 0, stream>>>(g2, W2T, nullptr, nullptr, 0.f,
                                               g1, h1, nullptr, 512, 2);
            // tr = rowsum(g1 * E1)
            tr_kernel<<<2048, 256, 0, stream>>>(g1, E1, trbuf[st]);
        }
        combine_kernel<<<2048, 256, 0, stream>>>(X, k1, k2, k3, k4, hstep / 6.f);
        ldcombine_kernel<<<32, 256, 0, stream>>>(ld, tr1, tr2, tr3, tr4, hstep / 6.f);
    }

    final_kernel<<<2080, 256, 0, stream>>>(X, ld, (float*)d_out);
}

// Round 2
// 4680.737 us; speedup vs baseline: 4.1830x; 4.1830x over previous
//
#include <hip/hip_runtime.h>
#include <math.h>
#include <stdint.h>

#define BATCH 8192
#define FEAT  64
#define HID   512
#define NS    16   // RK4 steps

typedef __attribute__((ext_vector_type(8))) short short8;
typedef __attribute__((ext_vector_type(4))) float f32x4;

__device__ inline unsigned short f2bf(float f) {
    union { float f; unsigned u; } v; v.f = f;
    unsigned r = v.u + 0x7fffu + ((v.u >> 16) & 1u);
    return (unsigned short)(r >> 16);
}
__device__ inline float bf2f(unsigned short h) {
    union { unsigned u; float f; } v; v.u = ((unsigned)h) << 16;
    return v.f;
}

__device__ inline void gload16(const void* g, void* l) {
    __builtin_amdgcn_global_load_lds(
        (const __attribute__((address_space(1))) unsigned*)g,
        (__attribute__((address_space(3))) unsigned*)l, 16, 0, 0);
}

// ---------------------------------------------------------------------------
// MFMA GEMM: C[M][N] = A[M][K](bf16) @ BT[N][K](bf16)^T with fused epilogues.
// 256 threads = 4 waves (2x2), wave tile (BM/2)x(BN/2), 16x16x32 bf16 MFMA.
// LDS tiles As[BM][64], Bs[BN][64] bf16, granule-XOR swizzled (T2-style):
// phys granule = logical_kg ^ (row&7); global_load_lds sources pre-swizzled.
// EPI: 0 = h1 (tanh(acc+bias+t*trow) -> bf16)
//      1 = h2 (tanh -> bf16; g2 = g3*(1-h^2) -> bf16)
//      2 = dx (acc+bias -> f32)
//      3 = g1/tr (rowsum(acc*(1-h1^2)*E1) -> atomicAdd tr)
// AXPY: stage A-tile on the fly from fp32 X + axc*Kf (K must be 64).
// ---------------------------------------------------------------------------
template<int BM, int BN, int EPI, bool AXPY>
__global__ __launch_bounds__(256) void gemm_mfma(
    const unsigned short* __restrict__ A,
    const float* __restrict__ Xf, const float* __restrict__ Kf, float axc,
    const unsigned short* __restrict__ BT, int K, int ldout,
    const float* __restrict__ bias, const float* __restrict__ trow, float tval,
    unsigned short* __restrict__ outb, float* __restrict__ outf,
    const float* __restrict__ g3, unsigned short* __restrict__ g2,
    const unsigned short* __restrict__ h1, const float* __restrict__ E1,
    float* __restrict__ tr)
{
    constexpr int MF = BM / 32;   // 16x16 frags per wave in M
    constexpr int NF = BN / 32;   // frags per wave in N
    const int row0 = blockIdx.x * BM;
    const int col0 = blockIdx.y * BN;
    const int tid  = threadIdx.x;
    const int wid  = tid >> 6;
    const int lane = tid & 63;
    const int wrow = (wid >> 1) * (BM / 2);
    const int wcol = (wid & 1) * (BN / 2);

    __shared__ unsigned short lds[(BM + BN) * 64];
    char* Ab = (char*)lds;            // BM*128 bytes
    char* Bb = Ab + BM * 128;         // BN*128 bytes

    f32x4 acc[MF][NF] = {};

    const int nsteps = K >> 6;
    for (int ks = 0; ks < nsteps; ++ks) {
        const int k0 = ks << 6;
        if (ks) __syncthreads();

        if constexpr (AXPY) {
            // A-tile computed from fp32: bf16(X + axc*Kf), K == 64
            #pragma unroll
            for (int i = 0; i < BM * 8 / 256; ++i) {
                int s   = i * 256 + tid;
                int row = s >> 3, kgp = s & 7, kgl = kgp ^ (row & 7);
                const float* xp = Xf + (size_t)(row0 + row) * 64 + kgl * 8;
                float v[8];
                #pragma unroll
                for (int j = 0; j < 8; ++j) v[j] = xp[j];
                if (Kf) {
                    const float* kp = Kf + (size_t)(row0 + row) * 64 + kgl * 8;
                    #pragma unroll
                    for (int j = 0; j < 8; ++j) v[j] += axc * kp[j];
                }
                short8 r;
                #pragma unroll
                for (int j = 0; j < 8; ++j) r[j] = (short)f2bf(v[j]);
                *(short8*)(Ab + (size_t)s * 16) = r;
            }
        } else {
            #pragma unroll
            for (int i = 0; i < BM * 8 / 256; ++i) {
                int base = ((wid * (BM * 8 / 256) + i) << 6);
                int s    = base + lane;
                int row  = s >> 3, kgp = s & 7, kgl = kgp ^ (row & 7);
                gload16(A + (size_t)(row0 + row) * K + k0 + kgl * 8,
                        Ab + (size_t)base * 16);
            }
        }
        #pragma unroll
        for (int i = 0; i < BN * 8 / 256; ++i) {
            int base = ((wid * (BN * 8 / 256) + i) << 6);
            int s    = base + lane;
            int cc   = s >> 3, kgp = s & 7, kgl = kgp ^ (cc & 7);
            gload16(BT + (size_t)(col0 + cc) * K + k0 + kgl * 8,
                    Bb + (size_t)base * 16);
        }
        __syncthreads();

        #pragma unroll
        for (int kh = 0; kh < 2; ++kh) {
            short8 af[MF], bfr[NF];
            #pragma unroll
            for (int m = 0; m < MF; ++m) {
                int row = wrow + m * 16 + (lane & 15);
                int kg  = kh * 4 + (lane >> 4);
                af[m] = *(const short8*)(Ab + row * 128 + ((kg ^ (row & 7)) << 4));
            }
            #pragma unroll
            for (int n = 0; n < NF; ++n) {
                int cc = wcol + n * 16 + (lane & 15);
                int kg = kh * 4 + (lane >> 4);
                bfr[n] = *(const short8*)(Bb + cc * 128 + ((kg ^ (cc & 7)) << 4));
            }
            #pragma unroll
            for (int m = 0; m < MF; ++m)
                #pragma unroll
                for (int n = 0; n < NF; ++n)
                    acc[m][n] = __builtin_amdgcn_mfma_f32_16x16x32_bf16(
                        af[m], bfr[n], acc[m][n], 0, 0, 0);
        }
    }

    // ---- epilogues ----
    if constexpr (EPI == 0) {        // h1 = tanh(acc + b1 + t*w1_t) -> bf16
        #pragma unroll
        for (int n = 0; n < NF; ++n) {
            int cc = col0 + wcol + n * 16 + (lane & 15);
            float bb = bias[cc] + tval * trow[cc];
            #pragma unroll
            for (int m = 0; m < MF; ++m) {
                int rbase = row0 + wrow + m * 16 + ((lane >> 4) << 2);
                #pragma unroll
                for (int r = 0; r < 4; ++r) {
                    float v = tanhf(acc[m][n][r] + bb);
                    outb[(size_t)(rbase + r) * ldout + cc] = f2bf(v);
                }
            }
        }
    } else if constexpr (EPI == 1) { // h2 -> bf16, g2 = g3*(1-h^2) -> bf16
        #pragma unroll
        for (int n = 0; n < NF; ++n) {
            int cc = col0 + wcol + n * 16 + (lane & 15);
            float bb = bias[cc];
            #pragma unroll
            for (int m = 0; m < MF; ++m) {
                int rbase = row0 + wrow + m * 16 + ((lane >> 4) << 2);
                #pragma unroll
                for (int r = 0; r < 4; ++r) {
                    size_t o = (size_t)(rbase + r) * ldout + cc;
                    float v = tanhf(acc[m][n][r] + bb);
                    outb[o] = f2bf(v);
                    g2[o]   = f2bf(g3[o] * (1.f - v * v));
                }
            }
        }
    } else if constexpr (EPI == 2) { // dx = acc + b3 -> f32
        #pragma unroll
        for (int n = 0; n < NF; ++n) {
            int cc = col0 + wcol + n * 16 + (lane & 15);
            float bb = bias[cc];
            #pragma unroll
            for (int m = 0; m < MF; ++m) {
                int rbase = row0 + wrow + m * 16 + ((lane >> 4) << 2);
                #pragma unroll
                for (int r = 0; r < 4; ++r)
                    outf[(size_t)(rbase + r) * ldout + cc] = acc[m][n][r] + bb;
            }
        }
    } else {                          // EPI 3: tr += rowsum(acc*(1-h1^2)*E1)
        #pragma unroll
        for (int m = 0; m < MF; ++m) {
            int rbase = row0 + wrow + m * 16 + ((lane >> 4) << 2);
            float rs[4] = {0.f, 0.f, 0.f, 0.f};
            #pragma unroll
            for (int n = 0; n < NF; ++n) {
                int cc = col0 + wcol + n * 16 + (lane & 15);
                #pragma unroll
                for (int r = 0; r < 4; ++r) {
                    size_t o = (size_t)(rbase + r) * HID + cc;
                    float hv = bf2f(h1[o]);
                    rs[r] += acc[m][n][r] * (1.f - hv * hv) * E1[o];
                }
            }
            #pragma unroll
            for (int r = 0; r < 4; ++r) {
                float v = rs[r];
                v += __shfl_xor(v, 1, 16);
                v += __shfl_xor(v, 2, 16);
                v += __shfl_xor(v, 4, 16);
                v += __shfl_xor(v, 8, 16);
                if ((lane & 15) == 0) atomicAdd(&tr[rbase + r], v);
            }
        }
    }
}

// --------------------------- precompute kernels ----------------------------
// fp32 tiled GEMM (used once per call for g3 = eps@W3^T and E1 = eps@W1[:64])
__global__ __launch_bounds__(256) void mlp_gemm(
    const float* __restrict__ A, const float* __restrict__ W,
    float* __restrict__ out, int K)
{
    const int bid  = blockIdx.x;
    const int row0 = (bid >> 1) << 4;
    const int j    = ((bid & 1) << 8) + threadIdx.x;

    __shared__ float As[16 * 64];
    float acc[16];
#pragma unroll
    for (int r = 0; r < 16; ++r) acc[r] = 0.f;

    for (int k0 = 0; k0 < K; k0 += 64) {
        __syncthreads();
        for (int tt = threadIdx.x; tt < 16 * 64; tt += 256) {
            int r = tt >> 6, k = tt & 63;
            As[tt] = A[(size_t)(row0 + r) * K + (k0 + k)];
        }
        __syncthreads();
        for (int k = 0; k < 64; k += 4) {
            float w0 = W[(size_t)(k0 + k + 0) * HID + j];
            float w1 = W[(size_t)(k0 + k + 1) * HID + j];
            float w2 = W[(size_t)(k0 + k + 2) * HID + j];
            float w3 = W[(size_t)(k0 + k + 3) * HID + j];
#pragma unroll
            for (int r = 0; r < 16; ++r) {
                float4 a = *(const float4*)&As[r * 64 + k];
                acc[r] += a.x * w0 + a.y * w1 + a.z * w2 + a.w * w3;
            }
        }
    }
#pragma unroll
    for (int r = 0; r < 16; ++r) out[(size_t)(row0 + r) * HID + j] = acc[r];
}

__global__ void transpose_kernel(const float* __restrict__ in, float* __restrict__ out,
                                 int R, int C)
{
    int idx = blockIdx.x * 256 + threadIdx.x;
    if (idx < R * C) { int r = idx / C, c = idx % C; out[c * R + r] = in[idx]; }
}

// bf16 weight prep: W1T[512][64], W2[512][512], W2T[512][512], W3T[64][512]
__global__ __launch_bounds__(256) void prep_weights(
    const float* __restrict__ W1, const float* __restrict__ W2,
    const float* __restrict__ W3,
    unsigned short* __restrict__ W1Tb, unsigned short* __restrict__ W2b,
    unsigned short* __restrict__ W2Tb, unsigned short* __restrict__ W3Tb)
{
    int idx = blockIdx.x * 256 + threadIdx.x;   // 0..262143
    W2b[idx] = f2bf(W2[idx]);
    int n = idx >> 9, k = idx & 511;
    W2Tb[idx] = f2bf(W2[k * 512 + n]);
    if (idx < 512 * 64) {
        int n2 = idx >> 6, k2 = idx & 63;
        W1Tb[idx] = f2bf(W1[k2 * 512 + n2]);     // W1T[n][k] = W1[k][n]
        int f = idx >> 9, h = idx & 511;
        W3Tb[idx] = f2bf(W3[h * 64 + f]);        // W3T[f][h] = W3[h][f]
    }
}

// ------------------------------ small kernels ------------------------------
__global__ __launch_bounds__(256) void combine_kernel(
    float* __restrict__ X, const float* __restrict__ k1, const float* __restrict__ k2,
    const float* __restrict__ k3, const float* __restrict__ k4, float h6)
{
    int n = blockIdx.x * 256 + threadIdx.x;
    X[n] += h6 * (k1[n] + 2.f * k2[n] + 2.f * k3[n] + k4[n]);
}

__global__ __launch_bounds__(256) void ldcombine_kernel(
    float* __restrict__ ld, float* __restrict__ t1, float* __restrict__ t2,
    float* __restrict__ t3, float* __restrict__ t4, float h6)
{
    int n = blockIdx.x * 256 + threadIdx.x;
    ld[n] -= h6 * (t1[n] + 2.f * t2[n] + 2.f * t3[n] + t4[n]);
    t1[n] = 0.f; t2[n] = 0.f; t3[n] = 0.f; t4[n] = 0.f;   // ready for next step
}

__global__ __launch_bounds__(256) void copy_kernel(const float* __restrict__ in,
                                                   float* __restrict__ out, int n)
{
    int i = blockIdx.x * 256 + threadIdx.x;
    if (i < n) out[i] = in[i];
}

__global__ __launch_bounds__(256) void zero_kernel(float* __restrict__ p, int n)
{
    int i = blockIdx.x * 256 + threadIdx.x;
    if (i < n) p[i] = 0.f;
}

__global__ __launch_bounds__(256) void final_kernel(
    const float* __restrict__ X, const float* __restrict__ ld, float* __restrict__ out)
{
    int n = blockIdx.x * 256 + threadIdx.x;
    const int NZ = BATCH * FEAT;
    if (n < NZ) out[n] = X[n];
    else if (n < NZ + BATCH) out[n] = ld[n - NZ];
}

// ---------------------------------------------------------------------------
extern "C" void kernel_launch(void* const* d_in, const int* in_sizes, int n_in,
                              void* d_out, int out_size, void* d_ws, size_t ws_size,
                              hipStream_t stream)
{
    const float* x   = (const float*)d_in[0];
    const float* eps = (const float*)d_in[1];
    const float* W1  = (const float*)d_in[2];
    const float* b1  = (const float*)d_in[3];
    const float* W2  = (const float*)d_in[4];
    const float* b2  = (const float*)d_in[5];
    const float* W3  = (const float*)d_in[6];
    const float* b3  = (const float*)d_in[7];
    (void)in_sizes; (void)n_in; (void)out_size; (void)ws_size;

    float* ws = (float*)d_ws;
    size_t off = 0;
    auto alloc = [&](size_t n) { float* p = ws + off; off += n; return p; };

    float* g3   = alloc((size_t)BATCH * HID);
    float* E1   = alloc((size_t)BATCH * HID);
    float* X    = alloc((size_t)BATCH * FEAT);
    float* k1   = alloc((size_t)BATCH * FEAT);
    float* k2   = alloc((size_t)BATCH * FEAT);
    float* k3   = alloc((size_t)BATCH * FEAT);
    float* k4   = alloc((size_t)BATCH * FEAT);
    float* W3Tf = alloc((size_t)FEAT * HID);
    float* tr1  = alloc(BATCH);
    float* tr2  = alloc(BATCH);
    float* tr3  = alloc(BATCH);
    float* tr4  = alloc(BATCH);
    float* ld   = alloc(BATCH);

    unsigned short* bws = (unsigned short*)(ws + off);
    size_t boff = 0;
    auto balloc = [&](size_t n) { unsigned short* p = bws + boff; boff += n; return p; };
    unsigned short* h1b  = balloc((size_t)BATCH * HID);
    unsigned short* h2b  = balloc((size_t)BATCH * HID);
    unsigned short* g2b  = balloc((size_t)BATCH * HID);
    unsigned short* W1Tb = balloc((size_t)HID * FEAT);
    unsigned short* W2b  = balloc((size_t)HID * HID);
    unsigned short* W2Tb = balloc((size_t)HID * HID);
    unsigned short* W3Tb = balloc((size_t)FEAT * HID);

    // ---- prologue (once per call) ----
    transpose_kernel<<<(HID * FEAT + 255) / 256, 256, 0, stream>>>(W3, W3Tf, HID, FEAT);
    prep_weights<<<1024, 256, 0, stream>>>(W1, W2, W3, W1Tb, W2b, W2Tb, W3Tb);
    mlp_gemm<<<1024, 256, 0, stream>>>(eps, W3Tf, g3, 64);   // g3 = eps @ W3^T
    mlp_gemm<<<1024, 256, 0, stream>>>(eps, W1, E1, 64);     // E1 = eps @ W1[:64]
    copy_kernel<<<2048, 256, 0, stream>>>(x, X, BATCH * FEAT);
    zero_kernel<<<160, 256, 0, stream>>>(tr1, 5 * BATCH);    // tr1..tr4 + ld

    const float hstep = 1.f / NS;
    float* kbuf[4]  = {k1, k2, k3, k4};
    float* trbuf[4] = {tr1, tr2, tr3, tr4};
    const dim3 g128(BATCH / 128, HID / 128);   // (64, 4)
    const dim3 gdx(BATCH / 64, 1);             // (128, 1)

    for (int s = 0; s < NS; ++s) {
        float t0 = s * hstep;
        const float cs[4]  = {0.f, 0.5f * hstep, 0.5f * hstep, hstep};
        const float tsv[4] = {t0, t0 + 0.5f * hstep, t0 + 0.5f * hstep, t0 + hstep};
        for (int st = 0; st < 4; ++st) {
            const float* kprev = st ? kbuf[st - 1] : nullptr;
            // h1 = tanh([X + c*k, t] @ W1 + b1)        (fused axpy in staging)
            gemm_mfma<128, 128, 0, true><<<g128, 256, 0, stream>>>(
                nullptr, X, kprev, cs[st], W1Tb, 64, HID,
                b1, W1 + (size_t)64 * HID, tsv[st],
                h1b, nullptr, nullptr, nullptr, nullptr, nullptr, nullptr);
            // h2 = tanh(h1 @ W2 + b2); g2 = g3*(1-h2^2)
            gemm_mfma<128, 128, 1, false><<<g128, 256, 0, stream>>>(
                h1b, nullptr, nullptr, 0.f, W2Tb, 512, HID,
                b2, nullptr, 0.f,
                h2b, nullptr, g3, g2b, nullptr, nullptr, nullptr);
            // dx = h2 @ W3 + b3
            gemm_mfma<64, 64, 2, false><<<gdx, 256, 0, stream>>>(
                h2b, nullptr, nullptr, 0.f, W3Tb, 512, FEAT,
                b3, nullptr, 0.f,
                nullptr, kbuf[st], nullptr, nullptr, nullptr, nullptr, nullptr);
            // tr += rowsum((g2 @ W2^T)*(1-h1^2)*E1)
            gemm_mfma<128, 128, 3, false><<<g128, 256, 0, stream>>>(
                g2b, nullptr, nullptr, 0.f, W2b, 512, HID,
                nullptr, nullptr, 0.f,
                nullptr, nullptr, nullptr, nullptr, h1b, E1, trbuf[st]);
        }
        combine_kernel<<<2048, 256, 0, stream>>>(X, k1, k2, k3, k4, hstep / 6.f);
        ldcombine_kernel<<<32, 256, 0, stream>>>(ld, tr1, tr2, tr3, tr4, hstep / 6.f);
    }

    final_kernel<<<2080, 256, 0, stream>>>(X, ld, (float*)d_out);
}

// Round 3
// 3081.334 us; speedup vs baseline: 6.3542x; 1.5191x over previous
//
#include <hip/hip_runtime.h>
#include <math.h>
#include <stdint.h>

#define BATCH 8192
#define FEAT  64
#define HID   512
#define NS    16   // RK4 steps

typedef __attribute__((ext_vector_type(8))) short short8;
typedef __attribute__((ext_vector_type(4))) float f32x4;

__device__ inline unsigned short f2bf(float f) {
    union { float f; unsigned u; } v; v.f = f;
    unsigned r = v.u + 0x7fffu + ((v.u >> 16) & 1u);
    return (unsigned short)(r >> 16);
}
__device__ inline float bf2f(unsigned short h) {
    union { unsigned u; float f; } v; v.u = ((unsigned)h) << 16;
    return v.f;
}

// Swizzled LDS [32 rows][512 cols] bf16, row stride 1024B, 16B granules,
// phys_granule = granule ^ (row&7)  (G4 bank-conflict fix).
__device__ inline void sto_bf(unsigned short* base, int row, int col, unsigned short v) {
    *(unsigned short*)((char*)base + row * 1024 +
                       ((((col >> 3) ^ (row & 7))) << 4) + ((col & 7) << 1)) = v;
}
__device__ inline float ld_bf(const unsigned short* base, int row, int col) {
    return bf2f(*(const unsigned short*)((const char*)base + row * 1024 +
                 ((((col >> 3) ^ (row & 7))) << 4) + ((col & 7) << 1)));
}

// ---------------------------------------------------------------------------
// Core MFMA loop: acc[2][NF] += A_lds(32 x 32*KS slice) @ Bpk^T.
// A: swizzled LDS, row stride RB bytes. B: pre-packed fragment order,
// slot index ((cb*KST + kb)*64 + lane), 16B per lane -> fully coalesced.
// ---------------------------------------------------------------------------
template<int KS, int KST, int NF, int RB>
__device__ inline void gemm_ab(const char* Al, const unsigned short* __restrict__ Bpk,
                               int cb0, int kb0, int lane, f32x4 acc[2][NF])
{
    const int l15 = lane & 15, l4 = lane >> 4;
#pragma unroll
    for (int ks = 0; ks < KS; ++ks) {
        short8 b[NF];
#pragma unroll
        for (int nf = 0; nf < NF; ++nf)
            b[nf] = *(const short8*)(Bpk + ((size_t)((cb0 + nf) * KST + kb0 + ks) * 64 + lane) * 8);
        short8 a[2];
#pragma unroll
        for (int m = 0; m < 2; ++m) {
            int row = m * 16 + l15;
            int g = (kb0 + ks) * 4 + l4;
            a[m] = *(const short8*)(Al + row * RB + ((g ^ (row & 7)) << 4));
        }
#pragma unroll
        for (int m = 0; m < 2; ++m)
#pragma unroll
            for (int nf = 0; nf < NF; ++nf)
                acc[m][nf] = __builtin_amdgcn_mfma_f32_16x16x32_bf16(
                    a[m], b[nf], acc[m][nf], 0, 0, 0);
    }
}

// ---------------------------------------------------------------------------
// Fully fused dyn eval. One block = 32 batch rows, 512 threads = 8 waves.
// Wave w owns columns [64w, 64w+64) of the 512-wide stages.
// STAGE 0..3 = RK4 stages; STAGE 3 also applies the RK4 combine + ld update.
// ---------------------------------------------------------------------------
template<int STAGE>
__global__ __launch_bounds__(512) void ffjord_eval(
    const float* __restrict__ Xc, float* __restrict__ Xm,
    const float* __restrict__ kin, float axc,
    const float* __restrict__ k1, const float* __restrict__ k2,
    const float* __restrict__ k3, float* __restrict__ kout,
    const unsigned short* __restrict__ W1Tpk, const float* __restrict__ b1,
    const float* __restrict__ w1t, float tval,
    const unsigned short* __restrict__ W2Tpk, const float* __restrict__ b2,
    const unsigned short* __restrict__ W2pk,
    const unsigned short* __restrict__ W3Tpk, const float* __restrict__ b3,
    const unsigned short* __restrict__ g3b, const unsigned short* __restrict__ E1b,
    float* __restrict__ trout,
    const float* __restrict__ tr1, const float* __restrict__ tr2,
    const float* __restrict__ tr3, float* __restrict__ ld, float h6)
{
    __shared__ unsigned short h1s[32 * 512];
    __shared__ unsigned short h2s[32 * 512];
    __shared__ unsigned short g2s[32 * 512];
    __shared__ unsigned short As[32 * 64];
    __shared__ float red[32 * 64];
    __shared__ float trp[8 * 32];

    const int tid = threadIdx.x, wid = tid >> 6, lane = tid & 63;
    const int l15 = lane & 15, l4 = lane >> 4;
    const int row0 = blockIdx.x * 32;

    // zero dx-reduction buffer
    *(f32x4*)&red[tid * 4] = (f32x4){0.f, 0.f, 0.f, 0.f};

    // ---- stage A: bf16([X + axc*kin]) -> LDS (swizzled) ----
    {
        int row = tid >> 4, c0 = (tid & 15) * 4;
        size_t o = (size_t)(row0 + row) * 64 + c0;
        float v0 = Xc[o], v1 = Xc[o + 1], v2 = Xc[o + 2], v3 = Xc[o + 3];
        if constexpr (STAGE != 0) {
            v0 += axc * kin[o]; v1 += axc * kin[o + 1];
            v2 += axc * kin[o + 2]; v3 += axc * kin[o + 3];
        }
        unsigned lo = (unsigned)f2bf(v0) | ((unsigned)f2bf(v1) << 16);
        unsigned hi = (unsigned)f2bf(v2) | ((unsigned)f2bf(v3) << 16);
        int g = c0 >> 3;
        char* p = (char*)As + row * 128 + ((g ^ (row & 7)) << 4) + ((c0 & 7) << 1);
        ((unsigned*)p)[0] = lo; ((unsigned*)p)[1] = hi;
    }
    __syncthreads();

    // ---- h1 = tanh(A @ W1[:64] + b1 + t*W1[64]) ----
    {
        f32x4 acc[2][4] = {};
        gemm_ab<2, 2, 4, 128>((const char*)As, W1Tpk, wid * 4, 0, lane, acc);
#pragma unroll
        for (int nf = 0; nf < 4; ++nf) {
            int col = wid * 64 + nf * 16 + l15;
            float bb = b1[col] + tval * w1t[col];
#pragma unroll
            for (int m = 0; m < 2; ++m)
#pragma unroll
                for (int r = 0; r < 4; ++r) {
                    int row = m * 16 + l4 * 4 + r;
                    float v = tanhf(acc[m][nf][r] + bb);
                    sto_bf(h1s, row, col, f2bf(v));
                }
        }
    }
    __syncthreads();

    // ---- h2 = tanh(h1 @ W2 + b2);  g2 = g3 * (1 - h2^2) ----
    {
        f32x4 acc[2][4] = {};
        gemm_ab<16, 16, 4, 1024>((const char*)h1s, W2Tpk, wid * 4, 0, lane, acc);
#pragma unroll
        for (int nf = 0; nf < 4; ++nf) {
            int col = wid * 64 + nf * 16 + l15;
            float bb = b2[col];
#pragma unroll
            for (int m = 0; m < 2; ++m)
#pragma unroll
                for (int r = 0; r < 4; ++r) {
                    int row = m * 16 + l4 * 4 + r;
                    float v = tanhf(acc[m][nf][r] + bb);
                    sto_bf(h2s, row, col, f2bf(v));
                    float g3v = bf2f(g3b[(size_t)(row0 + row) * HID + col]);
                    sto_bf(g2s, row, col, f2bf(g3v * (1.f - v * v)));
                }
        }
    }
    __syncthreads();

    // ---- dx partial: wave w takes k in [64w, 64w+64) of h2 @ W3 ----
    {
        f32x4 acc[2][4] = {};
        gemm_ab<2, 16, 4, 1024>((const char*)h2s, W3Tpk, 0, wid * 2, lane, acc);
#pragma unroll
        for (int m = 0; m < 2; ++m)
#pragma unroll
            for (int nf = 0; nf < 4; ++nf)
#pragma unroll
                for (int r = 0; r < 4; ++r) {
                    int row = m * 16 + l4 * 4 + r, col = nf * 16 + l15;
                    atomicAdd(&red[row * 64 + col], acc[m][nf][r]);
                }
    }
    __syncthreads();

    // ---- dx output (STAGE<3: store k; STAGE==3: RK4 combine into X) ----
    {
        int row = tid >> 4, c0 = (tid & 15) * 4;
        size_t o = (size_t)(row0 + row) * 64 + c0;
        float r0 = red[row * 64 + c0] + b3[c0];
        float r1 = red[row * 64 + c0 + 1] + b3[c0 + 1];
        float r2 = red[row * 64 + c0 + 2] + b3[c0 + 2];
        float r3 = red[row * 64 + c0 + 3] + b3[c0 + 3];
        if constexpr (STAGE < 3) {
            kout[o] = r0; kout[o + 1] = r1; kout[o + 2] = r2; kout[o + 3] = r3;
        } else {
            Xm[o]     += h6 * (k1[o]     + 2.f * k2[o]     + 2.f * k3[o]     + r0);
            Xm[o + 1] += h6 * (k1[o + 1] + 2.f * k2[o + 1] + 2.f * k3[o + 1] + r1);
            Xm[o + 2] += h6 * (k1[o + 2] + 2.f * k2[o + 2] + 2.f * k3[o + 2] + r2);
            Xm[o + 3] += h6 * (k1[o + 3] + 2.f * k2[o + 3] + 2.f * k3[o + 3] + r3);
        }
    }

    // ---- gt = g2 @ W2^T;  tr partial = rowsum(gt * (1-h1^2) * E1) ----
    {
        f32x4 acc[2][4] = {};
        gemm_ab<16, 16, 4, 1024>((const char*)g2s, W2pk, wid * 4, 0, lane, acc);
        float rs[2][4] = {{0.f, 0.f, 0.f, 0.f}, {0.f, 0.f, 0.f, 0.f}};
#pragma unroll
        for (int nf = 0; nf < 4; ++nf) {
            int col = wid * 64 + nf * 16 + l15;
#pragma unroll
            for (int m = 0; m < 2; ++m)
#pragma unroll
                for (int r = 0; r < 4; ++r) {
                    int row = m * 16 + l4 * 4 + r;
                    float h1v = ld_bf(h1s, row, col);
                    float e1v = bf2f(E1b[(size_t)(row0 + row) * HID + col]);
                    rs[m][r] += acc[m][nf][r] * (1.f - h1v * h1v) * e1v;
                }
        }
#pragma unroll
        for (int m = 0; m < 2; ++m)
#pragma unroll
            for (int r = 0; r < 4; ++r) {
                float v = rs[m][r];
                v += __shfl_xor(v, 1, 16);
                v += __shfl_xor(v, 2, 16);
                v += __shfl_xor(v, 4, 16);
                v += __shfl_xor(v, 8, 16);
                if (l15 == 0) trp[wid * 32 + m * 16 + l4 * 4 + r] = v;
            }
    }
    __syncthreads();

    if (tid < 32) {
        float s = 0.f;
#pragma unroll
        for (int w = 0; w < 8; ++w) s += trp[w * 32 + tid];
        if constexpr (STAGE < 3) {
            trout[row0 + tid] = s;
        } else {
            ld[row0 + tid] -= h6 * (tr1[row0 + tid] + 2.f * tr2[row0 + tid] +
                                    2.f * tr3[row0 + tid] + s);
        }
    }
}

// ---------------------------------------------------------------------------
// Weight pre-pack into MFMA B-fragment order (once per call).
// slot = (cb*KST + kb)*64 + lane;  n = cb*16 + (lane&15); k = kb*32 + (lane>>4)*8 + j
// ---------------------------------------------------------------------------
__global__ __launch_bounds__(256) void pack_weights(
    const float* __restrict__ W1, const float* __restrict__ W2,
    const float* __restrict__ W3,
    unsigned short* __restrict__ W1Tpk, unsigned short* __restrict__ W2Tpk,
    unsigned short* __restrict__ W2pk, unsigned short* __restrict__ W3Tpk)
{
    int s = blockIdx.x * 256 + threadIdx.x;   // 73728 slots
    unsigned short* dst; int KST, mode, base;
    if (s < 4096)       { dst = W1Tpk; KST = 2;  mode = 0; base = 0; }
    else if (s < 36864) { dst = W2Tpk; KST = 16; mode = 1; base = 4096; }
    else if (s < 69632) { dst = W2pk;  KST = 16; mode = 2; base = 36864; }
    else                { dst = W3Tpk; KST = 16; mode = 3; base = 69632; }
    int ls = s - base;
    int l = ls & 63, t = ls >> 6;
    int kb = t % KST, cb = t / KST;
    int n = cb * 16 + (l & 15);
    int k0 = kb * 32 + (l >> 4) * 8;
    unsigned short v[8];
#pragma unroll
    for (int j = 0; j < 8; ++j) {
        int k = k0 + j;
        float f = (mode == 0) ? W1[(size_t)k * HID + n]
                : (mode == 1) ? W2[(size_t)k * HID + n]
                : (mode == 2) ? W2[(size_t)n * HID + k]
                :               W3[(size_t)k * FEAT + n];
        v[j] = f2bf(f);
    }
    *(short8*)(dst + (size_t)ls * 8) = *(short8*)v;
}

// g3 = eps @ W3^T (BTRANS) or E1 = eps @ W1[:64]; out bf16 [8192][512]
template<bool BTRANS>
__global__ __launch_bounds__(256) void eps_gemm(
    const float* __restrict__ A, const float* __restrict__ W,
    unsigned short* __restrict__ out)
{
    const int row0 = (blockIdx.x >> 1) << 4;
    const int j = ((blockIdx.x & 1) << 8) + threadIdx.x;
    __shared__ float As_[16 * 64];
    for (int tt = threadIdx.x; tt < 1024; tt += 256) {
        int r = tt >> 6, k = tt & 63;
        As_[tt] = A[(size_t)(row0 + r) * 64 + k];
    }
    __syncthreads();
    float acc[16];
#pragma unroll
    for (int r = 0; r < 16; ++r) acc[r] = 0.f;
    for (int k = 0; k < 64; k += 4) {
        float w0, w1, w2, w3;
        if (BTRANS) {
            const float* p = W + (size_t)j * 64 + k;
            w0 = p[0]; w1 = p[1]; w2 = p[2]; w3 = p[3];
        } else {
            w0 = W[(size_t)(k + 0) * HID + j]; w1 = W[(size_t)(k + 1) * HID + j];
            w2 = W[(size_t)(k + 2) * HID + j]; w3 = W[(size_t)(k + 3) * HID + j];
        }
#pragma unroll
        for (int r = 0; r < 16; ++r) {
            float4 a = *(const float4*)&As_[r * 64 + k];
            acc[r] += a.x * w0 + a.y * w1 + a.z * w2 + a.w * w3;
        }
    }
#pragma unroll
    for (int r = 0; r < 16; ++r)
        out[(size_t)(row0 + r) * HID + j] = f2bf(acc[r]);
}

__global__ __launch_bounds__(256) void init_kernel(
    const float* __restrict__ x, float* __restrict__ X, float* __restrict__ ld)
{
    int i = blockIdx.x * 256 + threadIdx.x;
    if (i < BATCH * FEAT) X[i] = x[i];
    else if (i < BATCH * FEAT + BATCH) ld[i - BATCH * FEAT] = 0.f;
}

__global__ __launch_bounds__(256) void final_kernel(
    const float* __restrict__ X, const float* __restrict__ ld, float* __restrict__ out)
{
    int n = blockIdx.x * 256 + threadIdx.x;
    const int NZ = BATCH * FEAT;
    if (n < NZ) out[n] = X[n];
    else if (n < NZ + BATCH) out[n] = ld[n - NZ];
}

// ---------------------------------------------------------------------------
extern "C" void kernel_launch(void* const* d_in, const int* in_sizes, int n_in,
                              void* d_out, int out_size, void* d_ws, size_t ws_size,
                              hipStream_t stream)
{
    const float* x   = (const float*)d_in[0];
    const float* eps = (const float*)d_in[1];
    const float* W1  = (const float*)d_in[2];
    const float* b1  = (const float*)d_in[3];
    const float* W2  = (const float*)d_in[4];
    const float* b2  = (const float*)d_in[5];
    const float* W3  = (const float*)d_in[6];
    const float* b3  = (const float*)d_in[7];
    (void)in_sizes; (void)n_in; (void)out_size; (void)ws_size;

    float* ws = (float*)d_ws;
    size_t off = 0;
    auto alloc = [&](size_t n) { float* p = ws + off; off += n; return p; };

    float* X   = alloc((size_t)BATCH * FEAT);
    float* k1  = alloc((size_t)BATCH * FEAT);
    float* k2  = alloc((size_t)BATCH * FEAT);
    float* k3  = alloc((size_t)BATCH * FEAT);
    float* tr1 = alloc(BATCH);
    float* tr2 = alloc(BATCH);
    float* tr3 = alloc(BATCH);
    float* ld  = alloc(BATCH);

    unsigned short* bws = (unsigned short*)(ws + off);
    size_t boff = 0;
    auto balloc = [&](size_t n) { unsigned short* p = bws + boff; boff += n; return p; };
    unsigned short* g3b   = balloc((size_t)BATCH * HID);
    unsigned short* E1b   = balloc((size_t)BATCH * HID);
    unsigned short* W1Tpk = balloc((size_t)4096 * 8);
    unsigned short* W2Tpk = balloc((size_t)32768 * 8);
    unsigned short* W2pk  = balloc((size_t)32768 * 8);
    unsigned short* W3Tpk = balloc((size_t)4096 * 8);

    // ---- prologue ----
    pack_weights<<<288, 256, 0, stream>>>(W1, W2, W3, W1Tpk, W2Tpk, W2pk, W3Tpk);
    eps_gemm<true ><<<1024, 256, 0, stream>>>(eps, W3, g3b);   // g3 = eps @ W3^T
    eps_gemm<false><<<1024, 256, 0, stream>>>(eps, W1, E1b);   // E1 = eps @ W1[:64]
    init_kernel<<<(BATCH * FEAT + BATCH + 255) / 256, 256, 0, stream>>>(x, X, ld);

    const float h = 1.f / NS, h6 = h / 6.f;
    const float* w1t = W1 + (size_t)64 * HID;

    for (int s = 0; s < NS; ++s) {
        float t0 = s * h;
        ffjord_eval<0><<<256, 512, 0, stream>>>(
            X, nullptr, nullptr, 0.f, nullptr, nullptr, nullptr, k1,
            W1Tpk, b1, w1t, t0, W2Tpk, b2, W2pk, W3Tpk, b3,
            g3b, E1b, tr1, nullptr, nullptr, nullptr, nullptr, h6);
        ffjord_eval<1><<<256, 512, 0, stream>>>(
            X, nullptr, k1, 0.5f * h, nullptr, nullptr, nullptr, k2,
            W1Tpk, b1, w1t, t0 + 0.5f * h, W2Tpk, b2, W2pk, W3Tpk, b3,
            g3b, E1b, tr2, nullptr, nullptr, nullptr, nullptr, h6);
        ffjord_eval<2><<<256, 512, 0, stream>>>(
            X, nullptr, k2, 0.5f * h, nullptr, nullptr, nullptr, k3,
            W1Tpk, b1, w1t, t0 + 0.5f * h, W2Tpk, b2, W2pk, W3Tpk, b3,
            g3b, E1b, tr3, nullptr, nullptr, nullptr, nullptr, h6);
        ffjord_eval<3><<<256, 512, 0, stream>>>(
            X, X, k3, h, k1, k2, k3, nullptr,
            W1Tpk, b1, w1t, t0 + h, W2Tpk, b2, W2pk, W3Tpk, b3,
            g3b, E1b, nullptr, tr1, tr2, tr3, ld, h6);
    }

    final_kernel<<<2080, 256, 0, stream>>>(X, ld, (float*)d_out);
}

// Round 4
// 1452.766 us; speedup vs baseline: 13.4774x; 2.1210x over previous
//
#include <hip/hip_runtime.h>
#include <math.h>
#include <stdint.h>

#define BATCH 8192
#define FEAT  64
#define HID   512
#define NS    16   // RK4 steps

typedef __attribute__((ext_vector_type(8))) short short8;
typedef __attribute__((ext_vector_type(4))) float f32x4;

__device__ inline unsigned short f2bf(float f) {
    union { float f; unsigned u; } v; v.f = f;
    unsigned r = v.u + 0x7fffu + ((v.u >> 16) & 1u);
    return (unsigned short)(r >> 16);
}
__device__ inline float bf2f(unsigned short h) {
    union { unsigned u; float f; } v; v.u = ((unsigned)h) << 16;
    return v.f;
}
__device__ inline float fast_tanh(float x) {
    float e = __expf(2.f * x);
    return 1.f - 2.f * __builtin_amdgcn_rcpf(e + 1.f);
}

// Swizzled LDS bf16 tile, row stride RB bytes, 16B granules,
// phys_granule = granule ^ (row&7)  (G4 bank-conflict fix).
__device__ inline void sto_bf(unsigned short* base, int row, int col, unsigned short v) {
    *(unsigned short*)((char*)base + row * 1024 +
                       ((((col >> 3) ^ (row & 7))) << 4) + ((col & 7) << 1)) = v;
}
__device__ inline float ld_bf(const unsigned short* base, int row, int col) {
    return bf2f(*(const unsigned short*)((const char*)base + row * 1024 +
                 ((((col >> 3) ^ (row & 7))) << 4) + ((col & 7) << 1)));
}

// ---------------------------------------------------------------------------
// Core MFMA loop: acc[2][NF] += A_lds(32 rows x 32*KS k-slice) @ Bpk^T.
// A: swizzled LDS, row stride RB bytes. B: pre-packed fragment order,
// slot ((cb*KST + kb)*64 + lane), 16B per lane -> fully coalesced.
// ---------------------------------------------------------------------------
template<int KS, int KST, int NF, int RB>
__device__ inline void gemm_ab(const char* Al, const unsigned short* __restrict__ Bpk,
                               int cb0, int kb0, int lane, f32x4 acc[2][NF])
{
    const int l15 = lane & 15, l4 = lane >> 4;
#pragma unroll
    for (int ks = 0; ks < KS; ++ks) {
        short8 b[NF];
#pragma unroll
        for (int nf = 0; nf < NF; ++nf)
            b[nf] = *(const short8*)(Bpk + ((size_t)((cb0 + nf) * KST + kb0 + ks) * 64 + lane) * 8);
        short8 a[2];
#pragma unroll
        for (int m = 0; m < 2; ++m) {
            int row = m * 16 + l15;
            int g = (kb0 + ks) * 4 + l4;
            a[m] = *(const short8*)(Al + row * RB + ((g ^ (row & 7)) << 4));
        }
#pragma unroll
        for (int m = 0; m < 2; ++m)
#pragma unroll
            for (int nf = 0; nf < NF; ++nf)
                acc[m][nf] = __builtin_amdgcn_mfma_f32_16x16x32_bf16(
                    a[m], b[nf], acc[m][nf], 0, 0, 0);
    }
}

// ---------------------------------------------------------------------------
// Fully fused dyn eval. One block = 32 batch rows, 1024 threads = 16 waves.
// Wave w owns a 32-col slice of the 512-wide stages.
// STAGE 0..3 = RK4 stages; STAGE 3 applies the RK4 combine + ld update.
// ---------------------------------------------------------------------------
template<int STAGE>
__global__ __launch_bounds__(1024, 4) void ffjord_eval(
    const float* __restrict__ Xc, float* __restrict__ Xm,
    const float* __restrict__ kin, float axc,
    const float* __restrict__ k1, const float* __restrict__ k2,
    const float* __restrict__ k3, float* __restrict__ kout,
    const unsigned short* __restrict__ W1Tpk, const float* __restrict__ b1,
    const float* __restrict__ w1t, float tval,
    const unsigned short* __restrict__ W2Tpk, const float* __restrict__ b2,
    const unsigned short* __restrict__ W2pk,
    const unsigned short* __restrict__ W3Tpk, const float* __restrict__ b3,
    const unsigned short* __restrict__ G3, const unsigned short* __restrict__ E1B,
    float* __restrict__ trout,
    const float* __restrict__ tr1, const float* __restrict__ tr2,
    const float* __restrict__ tr3, float* __restrict__ ld, float h6)
{
    __shared__ unsigned short h1s[32 * 512];   // h1, then F1=(1-h1^2)*E1
    __shared__ unsigned short h2s[32 * 512];   // h2, then g2=g3*(1-h2^2)
    __shared__ unsigned short As[32 * 64];
    __shared__ float trp[16 * 32];

    const int tid = threadIdx.x, wid = tid >> 6, lane = tid & 63;
    const int l15 = lane & 15, l4 = lane >> 4;
    const int row0 = blockIdx.x * 32;

    // ---- phase 1: bf16(X + axc*kin) -> As (swizzled). 2 elems/thread ----
    {
        int row = tid >> 5, c0 = (tid & 31) * 2;
        size_t o = (size_t)(row0 + row) * 64 + c0;
        float v0 = Xc[o], v1 = Xc[o + 1];
        if constexpr (STAGE != 0) { v0 += axc * kin[o]; v1 += axc * kin[o + 1]; }
        unsigned pk = (unsigned)f2bf(v0) | ((unsigned)f2bf(v1) << 16);
        int g = c0 >> 3;
        *(unsigned*)((char*)As + row * 128 + ((g ^ (row & 7)) << 4) + ((c0 & 7) << 1)) = pk;
    }
    __syncthreads();

    // ---- phase 2: h1 = tanh(A @ W1[:64] + b1 + t*W1[64]) ----
    {
        f32x4 acc[2][2] = {};
        gemm_ab<2, 2, 2, 128>((const char*)As, W1Tpk, wid * 2, 0, lane, acc);
#pragma unroll
        for (int nf = 0; nf < 2; ++nf) {
            int col = wid * 32 + nf * 16 + l15;
            float bb = b1[col] + tval * w1t[col];
#pragma unroll
            for (int m = 0; m < 2; ++m)
#pragma unroll
                for (int r = 0; r < 4; ++r) {
                    int row = m * 16 + l4 * 4 + r;
                    sto_bf(h1s, row, col, f2bf(fast_tanh(acc[m][nf][r] + bb)));
                }
        }
    }
    __syncthreads();

    // ---- phase 3: h2 = tanh(h1 @ W2 + b2) ----
    {
        f32x4 acc[2][2] = {};
        gemm_ab<16, 16, 2, 1024>((const char*)h1s, W2Tpk, wid * 2, 0, lane, acc);
#pragma unroll
        for (int nf = 0; nf < 2; ++nf) {
            int col = wid * 32 + nf * 16 + l15;
            float bb = b2[col];
#pragma unroll
            for (int m = 0; m < 2; ++m)
#pragma unroll
                for (int r = 0; r < 4; ++r) {
                    int row = m * 16 + l4 * 4 + r;
                    sto_bf(h2s, row, col, f2bf(fast_tanh(acc[m][nf][r] + bb)));
                }
        }
    }
    __syncthreads();

    // ---- phase 4: g3 prefetch (all); waves 0-3: dx full-K GEMM -> global;
    //      waves 8-15: F1 = (1-h1^2)*E1 in-place into h1s ----
    const int prow = tid >> 5, pc0 = (tid & 31) * 8, pc1 = pc0 + 256;
    const size_t pbase = (size_t)(row0 + prow) * HID;
    short8 g3x = *(const short8*)(G3 + pbase + pc0);
    short8 g3y = *(const short8*)(G3 + pbase + pc1);

    if (wid < 4) {
        f32x4 acc[2][1] = {};
        gemm_ab<16, 16, 1, 1024>((const char*)h2s, W3Tpk, wid, 0, lane, acc);
        int col = wid * 16 + l15;
        float bb = b3[col];
#pragma unroll
        for (int m = 0; m < 2; ++m)
#pragma unroll
            for (int r = 0; r < 4; ++r) {
                int row = m * 16 + l4 * 4 + r;
                size_t o = (size_t)(row0 + row) * 64 + col;
                float v = acc[m][0][r] + bb;
                if constexpr (STAGE < 3) kout[o] = v;
                else Xm[o] += h6 * (k1[o] + 2.f * k2[o] + 2.f * k3[o] + v);
            }
    } else if (wid >= 8) {
        int tt = tid - 512;                  // 0..511
        int row = tt >> 4, cb = (tt & 15) * 32;
        size_t gb = (size_t)(row0 + row) * HID + cb;
        short8 e[4];
#pragma unroll
        for (int q = 0; q < 4; ++q) e[q] = *(const short8*)(E1B + gb + q * 8);
#pragma unroll
        for (int q = 0; q < 4; ++q) {
            int c = cb + q * 8;
            char* p = (char*)h1s + row * 1024 + ((((c >> 3) ^ (row & 7))) << 4);
            short8 h = *(short8*)p;
            short8 f;
#pragma unroll
            for (int j = 0; j < 8; ++j) {
                float hv = bf2f((unsigned short)h[j]);
                f[j] = (short)f2bf((1.f - hv * hv) * bf2f((unsigned short)e[q][j]));
            }
            *(short8*)p = f;
        }
    }
    __syncthreads();

    // ---- phase 5: g2 = g3*(1-h2^2) in-place into h2s (all threads) ----
    {
        char* p0 = (char*)h2s + prow * 1024 + ((((pc0 >> 3) ^ (prow & 7))) << 4);
        char* p1 = (char*)h2s + prow * 1024 + ((((pc1 >> 3) ^ (prow & 7))) << 4);
        short8 a0 = *(short8*)p0, a1 = *(short8*)p1, r0, r1;
#pragma unroll
        for (int j = 0; j < 8; ++j) {
            float v = bf2f((unsigned short)a0[j]);
            r0[j] = (short)f2bf(bf2f((unsigned short)g3x[j]) * (1.f - v * v));
        }
#pragma unroll
        for (int j = 0; j < 8; ++j) {
            float v = bf2f((unsigned short)a1[j]);
            r1[j] = (short)f2bf(bf2f((unsigned short)g3y[j]) * (1.f - v * v));
        }
        *(short8*)p0 = r0; *(short8*)p1 = r1;
    }
    __syncthreads();

    // ---- phase 6: gt = g2 @ W2^T; tr partial = rowsum(gt * F1) ----
    {
        f32x4 acc[2][2] = {};
        gemm_ab<16, 16, 2, 1024>((const char*)h2s, W2pk, wid * 2, 0, lane, acc);
        float rs[2][4] = {{0.f, 0.f, 0.f, 0.f}, {0.f, 0.f, 0.f, 0.f}};
#pragma unroll
        for (int nf = 0; nf < 2; ++nf) {
            int col = wid * 32 + nf * 16 + l15;
#pragma unroll
            for (int m = 0; m < 2; ++m)
#pragma unroll
                for (int r = 0; r < 4; ++r) {
                    int row = m * 16 + l4 * 4 + r;
                    rs[m][r] += acc[m][nf][r] * ld_bf(h1s, row, col);
                }
        }
#pragma unroll
        for (int m = 0; m < 2; ++m)
#pragma unroll
            for (int r = 0; r < 4; ++r) {
                float v = rs[m][r];
                v += __shfl_xor(v, 1, 16);
                v += __shfl_xor(v, 2, 16);
                v += __shfl_xor(v, 4, 16);
                v += __shfl_xor(v, 8, 16);
                if (l15 == 0) trp[wid * 32 + m * 16 + l4 * 4 + r] = v;
            }
    }
    __syncthreads();

    if (tid < 32) {
        float s = 0.f;
#pragma unroll
        for (int w = 0; w < 16; ++w) s += trp[w * 32 + tid];
        if constexpr (STAGE < 3) {
            trout[row0 + tid] = s;
        } else {
            ld[row0 + tid] -= h6 * (tr1[row0 + tid] + 2.f * tr2[row0 + tid] +
                                    2.f * tr3[row0 + tid] + s);
        }
    }
}

// ---------------------------------------------------------------------------
// Weight pre-pack into MFMA B-fragment order (once per call).
// slot = (cb*KST + kb)*64 + lane;  n = cb*16 + (lane&15); k = kb*32 + (lane>>4)*8 + j
// ---------------------------------------------------------------------------
__global__ __launch_bounds__(256) void pack_weights(
    const float* __restrict__ W1, const float* __restrict__ W2,
    const float* __restrict__ W3,
    unsigned short* __restrict__ W1Tpk, unsigned short* __restrict__ W2Tpk,
    unsigned short* __restrict__ W2pk, unsigned short* __restrict__ W3Tpk)
{
    int s = blockIdx.x * 256 + threadIdx.x;   // 73728 slots
    unsigned short* dst; int KST, mode, base;
    if (s < 4096)       { dst = W1Tpk; KST = 2;  mode = 0; base = 0; }
    else if (s < 36864) { dst = W2Tpk; KST = 16; mode = 1; base = 4096; }
    else if (s < 69632) { dst = W2pk;  KST = 16; mode = 2; base = 36864; }
    else                { dst = W3Tpk; KST = 16; mode = 3; base = 69632; }
    int ls = s - base;
    int l = ls & 63, t = ls >> 6;
    int kb = t % KST, cb = t / KST;
    int n = cb * 16 + (l & 15);
    int k0 = kb * 32 + (l >> 4) * 8;
    unsigned short v[8];
#pragma unroll
    for (int j = 0; j < 8; ++j) {
        int k = k0 + j;
        float f = (mode == 0) ? W1[(size_t)k * HID + n]
                : (mode == 1) ? W2[(size_t)k * HID + n]
                : (mode == 2) ? W2[(size_t)n * HID + k]
                :               W3[(size_t)k * FEAT + n];
        v[j] = f2bf(f);
    }
    *(short8*)(dst + (size_t)ls * 8) = *(short8*)v;
}

// g3 = eps @ W3^T (BTRANS) or E1 = eps @ W1[:64]; out bf16 [8192][512]
template<bool BTRANS>
__global__ __launch_bounds__(256) void eps_gemm(
    const float* __restrict__ A, const float* __restrict__ W,
    unsigned short* __restrict__ out)
{
    const int row0 = (blockIdx.x >> 1) << 4;
    const int j = ((blockIdx.x & 1) << 8) + threadIdx.x;
    __shared__ float As_[16 * 64];
    for (int tt = threadIdx.x; tt < 1024; tt += 256) {
        int r = tt >> 6, k = tt & 63;
        As_[tt] = A[(size_t)(row0 + r) * 64 + k];
    }
    __syncthreads();
    float acc[16];
#pragma unroll
    for (int r = 0; r < 16; ++r) acc[r] = 0.f;
    for (int k = 0; k < 64; k += 4) {
        float w0, w1, w2, w3;
        if (BTRANS) {
            const float* p = W + (size_t)j * 64 + k;
            w0 = p[0]; w1 = p[1]; w2 = p[2]; w3 = p[3];
        } else {
            w0 = W[(size_t)(k + 0) * HID + j]; w1 = W[(size_t)(k + 1) * HID + j];
            w2 = W[(size_t)(k + 2) * HID + j]; w3 = W[(size_t)(k + 3) * HID + j];
        }
#pragma unroll
        for (int r = 0; r < 16; ++r) {
            float4 a = *(const float4*)&As_[r * 64 + k];
            acc[r] += a.x * w0 + a.y * w1 + a.z * w2 + a.w * w3;
        }
    }
#pragma unroll
    for (int r = 0; r < 16; ++r)
        out[(size_t)(row0 + r) * HID + j] = f2bf(acc[r]);
}

__global__ __launch_bounds__(256) void init_kernel(
    const float* __restrict__ x, float* __restrict__ X, float* __restrict__ ld)
{
    int i = blockIdx.x * 256 + threadIdx.x;
    if (i < BATCH * FEAT) X[i] = x[i];
    else if (i < BATCH * FEAT + BATCH) ld[i - BATCH * FEAT] = 0.f;
}

__global__ __launch_bounds__(256) void final_kernel(
    const float* __restrict__ X, const float* __restrict__ ld, float* __restrict__ out)
{
    int n = blockIdx.x * 256 + threadIdx.x;
    const int NZ = BATCH * FEAT;
    if (n < NZ) out[n] = X[n];
    else if (n < NZ + BATCH) out[n] = ld[n - NZ];
}

// ---------------------------------------------------------------------------
extern "C" void kernel_launch(void* const* d_in, const int* in_sizes, int n_in,
                              void* d_out, int out_size, void* d_ws, size_t ws_size,
                              hipStream_t stream)
{
    const float* x   = (const float*)d_in[0];
    const float* eps = (const float*)d_in[1];
    const float* W1  = (const float*)d_in[2];
    const float* b1  = (const float*)d_in[3];
    const float* W2  = (const float*)d_in[4];
    const float* b2  = (const float*)d_in[5];
    const float* W3  = (const float*)d_in[6];
    const float* b3  = (const float*)d_in[7];
    (void)in_sizes; (void)n_in; (void)out_size; (void)ws_size;

    float* ws = (float*)d_ws;
    size_t off = 0;
    auto alloc = [&](size_t n) { float* p = ws + off; off += n; return p; };

    float* X   = alloc((size_t)BATCH * FEAT);
    float* k1  = alloc((size_t)BATCH * FEAT);
    float* k2  = alloc((size_t)BATCH * FEAT);
    float* k3  = alloc((size_t)BATCH * FEAT);
    float* tr1 = alloc(BATCH);
    float* tr2 = alloc(BATCH);
    float* tr3 = alloc(BATCH);
    float* ld  = alloc(BATCH);

    unsigned short* bws = (unsigned short*)(ws + off);
    size_t boff = 0;
    auto balloc = [&](size_t n) { unsigned short* p = bws + boff; boff += n; return p; };
    unsigned short* g3b   = balloc((size_t)BATCH * HID);
    unsigned short* E1b   = balloc((size_t)BATCH * HID);
    unsigned short* W1Tpk = balloc((size_t)4096 * 8);
    unsigned short* W2Tpk = balloc((size_t)32768 * 8);
    unsigned short* W2pk  = balloc((size_t)32768 * 8);
    unsigned short* W3Tpk = balloc((size_t)4096 * 8);

    // ---- prologue ----
    pack_weights<<<288, 256, 0, stream>>>(W1, W2, W3, W1Tpk, W2Tpk, W2pk, W3Tpk);
    eps_gemm<true ><<<1024, 256, 0, stream>>>(eps, W3, g3b);   // g3 = eps @ W3^T
    eps_gemm<false><<<1024, 256, 0, stream>>>(eps, W1, E1b);   // E1 = eps @ W1[:64]
    init_kernel<<<(BATCH * FEAT + BATCH + 255) / 256, 256, 0, stream>>>(x, X, ld);

    const float h = 1.f / NS, h6 = h / 6.f;
    const float* w1t = W1 + (size_t)64 * HID;

    for (int s = 0; s < NS; ++s) {
        float t0 = s * h;
        ffjord_eval<0><<<256, 1024, 0, stream>>>(
            X, nullptr, nullptr, 0.f, nullptr, nullptr, nullptr, k1,
            W1Tpk, b1, w1t, t0, W2Tpk, b2, W2pk, W3Tpk, b3,
            g3b, E1b, tr1, nullptr, nullptr, nullptr, nullptr, h6);
        ffjord_eval<1><<<256, 1024, 0, stream>>>(
            X, nullptr, k1, 0.5f * h, nullptr, nullptr, nullptr, k2,
            W1Tpk, b1, w1t, t0 + 0.5f * h, W2Tpk, b2, W2pk, W3Tpk, b3,
            g3b, E1b, tr2, nullptr, nullptr, nullptr, nullptr, h6);
        ffjord_eval<2><<<256, 1024, 0, stream>>>(
            X, nullptr, k2, 0.5f * h, nullptr, nullptr, nullptr, k3,
            W1Tpk, b1, w1t, t0 + 0.5f * h, W2Tpk, b2, W2pk, W3Tpk, b3,
            g3b, E1b, tr3, nullptr, nullptr, nullptr, nullptr, h6);
        ffjord_eval<3><<<256, 1024, 0, stream>>>(
            X, X, k3, h, k1, k2, k3, nullptr,
            W1Tpk, b1, w1t, t0 + h, W2Tpk, b2, W2pk, W3Tpk, b3,
            g3b, E1b, nullptr, tr1, tr2, tr3, ld, h6);
    }

    final_kernel<<<2080, 256, 0, stream>>>(X, ld, (float*)d_out);
}